// Round 3
// baseline (106.999 us; speedup 1.0000x reference)
//
#include <hip/hip_runtime.h>
#include <hip/hip_bf16.h>

// Problem constants (match reference)
#define KK    5
#define PADV  2
#define NB    4
#define NC    32
#define NH    192
#define NW    192
#define NHO   96
#define NWO   96
#define NPX   (NHO * NWO)        // 9216
#define NPLANE (NB * NC * NPX)   // 1,179,648
#define EPSF  1e-20f
#define TP    32                 // output pixels per block (within one row)

__device__ __forceinline__ float softplusf(float x) {
    return fmaxf(x, 0.f) + log1pf(expf(-fabsf(x)));
}

__global__ __launch_bounds__(256) void fused_kernel(
    const float* __restrict__ dg,
    const float* __restrict__ cdg,
    const float* __restrict__ sg,
    const float* __restrict__ csg,
    const float* __restrict__ wsfdg,   // (1,)
    const float* __restrict__ wpropg,  // (32,)
    const float* __restrict__ spwg,    // (32*25,)
    const float* __restrict__ chwg,    // (32*32,)
    const float* __restrict__ biasg,   // (32,)
    float* __restrict__ out)
{
    __shared__ float sw_s[NC * 25];   // softplus(spatial_weight)
    __shared__ float cw_s[NC * NC];   // softplus(channel_weight)
    __shared__ float wp_s[NC];        // softplus(w_prop)
    __shared__ float red[256];
    __shared__ float A_s[NC][TP];     // cs_spatial * s_spatial
    __shared__ float B_s[NC][TP];     // cs_spatial
    __shared__ float S_s[NC][TP];     // s_from_d
    __shared__ float C_s[NC][TP];     // cs_from_d
    __shared__ float scal[3];         // sum_sw, sum_cw, sigmoid(w_s_from_d)

    const int t   = threadIdx.x;
    const int b   = blockIdx.y;
    const int px0 = blockIdx.x * TP;

    // ---------- phase 0: weight preprocessing (per-block, cheap) ----------
    float part = 0.f;
    for (int i = t; i < NC * 25; i += 256) {
        float v = softplusf(spwg[i]); sw_s[i] = v; part += v;
    }
    red[t] = part; __syncthreads();
    for (int s2 = 128; s2 > 0; s2 >>= 1) { if (t < s2) red[t] += red[t + s2]; __syncthreads(); }
    if (t == 0) scal[0] = red[0];
    __syncthreads();

    part = 0.f;
    for (int i = t; i < NC * NC; i += 256) {
        float v = softplusf(chwg[i]); cw_s[i] = v; part += v;
    }
    red[t] = part; __syncthreads();
    for (int s2 = 128; s2 > 0; s2 >>= 1) { if (t < s2) red[t] += red[t + s2]; __syncthreads(); }
    if (t == 0) {
        scal[1] = red[0];
        scal[2] = 1.f / (1.f + expf(-wsfdg[0]));
    }
    if (t < NC) wp_s[t] = softplusf(wpropg[t]);
    __syncthreads();

    const float sumsw = scal[0];
    const float sumcw = scal[1];
    const float wsfd  = scal[2];

    // ---------- phase 1: per-(channel, pixel) window pass ----------
#pragma unroll
    for (int k = 0; k < (NC * TP) / 256; k++) {   // 4 iterations
        const int item = t + 256 * k;
        const int c = item >> 5;          // 8 channels per iteration
        const int p = item & 31;
        const int px = px0 + p;
        const int ho = px / NWO;
        const int wo = px % NWO;
        const int base = ((b * NC) + c) * NH * NW;
        const float* __restrict__ dp  = dg  + base;
        const float* __restrict__ cdp = cdg + base;
        const float* __restrict__ sp  = sg  + base;
        const float* __restrict__ csp = csg + base;

        float bestmax = -INFINITY, bestmin = -INFINITY;
        float dmaxv = 0.f, cdmaxv = 0.f, dminv = 0.f, cdminv = 0.f;
        float nom = 0.f, den = 0.f;

#pragma unroll
        for (int dy = 0; dy < KK; dy++) {
            const int iy = ho * 2 + dy - PADV;
            const bool yok = (unsigned)iy < NH;
#pragma unroll
            for (int dx = 0; dx < KK; dx++) {
                const int ix = wo * 2 + dx - PADV;
                if (yok && (unsigned)ix < NW) {
                    const int idx = iy * NW + ix;
                    const float dv  = dp[idx];
                    const float cdv = cdp[idx];
                    const float vmax = dv * cdv;           // IEEE f32, matches np
                    if (vmax > bestmax) { bestmax = vmax; dmaxv = dv; cdmaxv = cdv; }
                    const float vmin = cdv / (dv + EPSF);  // IEEE f32 div, matches np
                    if (vmin > bestmin) { bestmin = vmin; dminv = dv; cdminv = cdv; }
                    const float sv  = sp[idx];
                    const float csv = csp[idx];
                    const float w = sw_s[c * 25 + dy * 5 + dx];
                    nom += w * (csv * sv);
                    den += w * csv;
                }
            }
        }

        const float mdm  = fabsf(dminv / (dmaxv + EPSF));
        const float sfd  = (1.f - wsfd) * mdm + wsfd * mdm * mdm;
        const float cfd  = cdmaxv * cdminv;
        const float ssp  = nom / (den + EPSF);
        const float cssp = den / (sumsw + EPSF);

        A_s[c][p] = cssp * ssp;
        B_s[c][p] = cssp;
        S_s[c][p] = sfd;
        C_s[c][p] = cfd;
    }
    __syncthreads();

    // ---------- phase 2: channel mix + final combine ----------
#pragma unroll
    for (int k = 0; k < (NC * TP) / 256; k++) {   // 4 iterations
        const int item = t + 256 * k;
        const int o = item >> 5;
        const int p = item & 31;
        const int px = px0 + p;

        float nom = 0.f, den = 0.f;
#pragma unroll
        for (int i = 0; i < NC; i++) {
            const float w = cw_s[o * NC + i];
            nom += w * A_s[i][p];
            den += w * B_s[i][p];
        }

        const float smix  = nom / (den + EPSF);
        const float csmix = den / (sumcw + EPSF);
        const float wp    = wp_s[o];
        const float sfd   = S_s[o][p];
        const float cfd   = C_s[o][p];

        float sout  = (wp * csmix * smix + cfd * sfd) / (wp * csmix + cfd + EPSF);
        const float csout = (wp * csmix + cfd) / (wp + 1.f);

        sout += biasg[o];
        sout = 1.f / (1.f + expf(-(sout * 2.f - 1.f))) * 0.5f + 0.5f;

        const int oidx = ((b * NC) + o) * NPX + px;
        out[oidx]           = sout;
        out[NPLANE + oidx]  = csout * 0.25f;
    }
}

extern "C" void kernel_launch(void* const* d_in, const int* in_sizes, int n_in,
                              void* d_out, int out_size, void* d_ws, size_t ws_size,
                              hipStream_t stream) {
    const float* d     = (const float*)d_in[0];
    const float* cd    = (const float*)d_in[1];
    const float* s     = (const float*)d_in[2];
    const float* cs    = (const float*)d_in[3];
    const float* wsfd  = (const float*)d_in[4];
    const float* wprop = (const float*)d_in[5];
    const float* spw   = (const float*)d_in[6];
    const float* chw   = (const float*)d_in[7];
    const float* bias  = (const float*)d_in[8];
    float* out = (float*)d_out;

    fused_kernel<<<dim3(NPX / TP, NB), 256, 0, stream>>>(
        d, cd, s, cs, wsfd, wprop, spw, chw, bias, out);
}

// Round 4
// 88.734 us; speedup vs baseline: 1.2058x; 1.2058x over previous
//
#include <hip/hip_runtime.h>

// Problem constants (match reference)
#define KK    5
#define PADV  2
#define NB    4
#define NC    32
#define NH    192
#define NW    192
#define NHO   96
#define NWO   96
#define NPX   (NHO * NWO)        // 9216
#define NPLANE (NB * NC * NPX)   // 1,179,648
#define EPSF  1e-20f
#define TW    8                  // tile width  (output px)
#define TH    4                  // tile height (output px)
#define TP    (TW * TH)          // 32 px per block
#define TPP   33                 // padded leading dim (bank-conflict-free)

__device__ __forceinline__ float softplusf(float x) {
    return fmaxf(x, 0.f) + log1pf(expf(-fabsf(x)));
}

__global__ __launch_bounds__(256, 4) void fused_kernel(
    const float* __restrict__ dg,
    const float* __restrict__ cdg,
    const float* __restrict__ sg,
    const float* __restrict__ csg,
    const float* __restrict__ wsfdg,   // (1,)
    const float* __restrict__ wpropg,  // (32,)
    const float* __restrict__ spwg,    // (32*25,)
    const float* __restrict__ chwg,    // (32*32,)
    const float* __restrict__ biasg,   // (32,)
    float* __restrict__ out)
{
    __shared__ float sw_s[NC * 25];
    __shared__ float cw_s[NC * NC];
    __shared__ float wp_s[NC];
    __shared__ float bias_s[NC];
    __shared__ float A_s[NC][TPP];   // cs_spatial * s_spatial
    __shared__ float B_s[NC][TPP];   // cs_spatial
    __shared__ float S_s[NC][TPP];   // s_from_d
    __shared__ float C_s[NC][TPP];   // cs_from_d
    __shared__ float red[8];
    __shared__ float scal[3];

    const int t = threadIdx.x;
    const int b = blockIdx.z;
    const int tile_x = blockIdx.x * TW;
    const int tile_y = blockIdx.y * TH;

    // ---------------- phase 0: weights (per-block, shuffle-reduced) ----------------
    float p_sw = 0.f, p_cw = 0.f;
    for (int i = t; i < NC * 25; i += 256) { float v = softplusf(spwg[i]); sw_s[i] = v; p_sw += v; }
    for (int i = t; i < NC * NC; i += 256) { float v = softplusf(chwg[i]); cw_s[i] = v; p_cw += v; }
    if (t < NC) { wp_s[t] = softplusf(wpropg[t]); bias_s[t] = biasg[t]; }
#pragma unroll
    for (int m = 32; m >= 1; m >>= 1) {
        p_sw += __shfl_xor(p_sw, m, 64);
        p_cw += __shfl_xor(p_cw, m, 64);
    }
    if ((t & 63) == 0) { red[(t >> 6) * 2] = p_sw; red[(t >> 6) * 2 + 1] = p_cw; }
    __syncthreads();
    if (t == 0) {
        scal[0] = red[0] + red[2] + red[4] + red[6];
        scal[1] = red[1] + red[3] + red[5] + red[7];
        scal[2] = 1.f / (1.f + expf(-wsfdg[0]));
    }
    __syncthreads();

    const float sumsw = scal[0];
    const float sumcw = scal[1];
    const float wsfd  = scal[2];

    // ---------------- phase 1: 2x2-blocked window pass ----------------
    // thread -> (channel c, 2x2 output block at rows oy0..oy0+1, cols ox0..ox0+1)
    const int c  = t >> 3;
    const int tr = (t >> 2) & 1;
    const int q  = t & 3;
    const int oy0 = tile_y + tr * 2;
    const int ox0 = tile_x + q * 2;
    const int cb = ox0 * 2 - 2;          // leftmost input col of 7-col union
    const int rb = oy0 * 2 - 2;          // topmost input row of 7-row union
    const size_t base = ((size_t)(b * NC) + c) * NH * NW;
    const float* __restrict__ dp  = dg  + base;
    const float* __restrict__ cdp = cdg + base;
    const float* __restrict__ sp  = sg  + base;
    const float* __restrict__ csp = csg + base;

    bool slotok[4];
#pragma unroll
    for (int k = 0; k < 4; k++) slotok[k] = (cb + 2 * k >= 0) && (cb + 2 * k + 1 < NW);
    bool ciok[7];
#pragma unroll
    for (int ci = 0; ci < 7; ci++) ciok[ci] = ((unsigned)(cb + ci) < NW);

    float bm[2][2], dM[2][2], cM[2][2];   // max-tracker: best, d@max, cd@max
    float bn[2][2], dN[2][2], cN[2][2];   // min-tracker
    float nom[2][2], den[2][2];
#pragma unroll
    for (int r = 0; r < 2; r++)
#pragma unroll
        for (int q2 = 0; q2 < 2; q2++) {
            bm[r][q2] = -INFINITY; bn[r][q2] = -INFINITY;
            dM[r][q2] = 0.f; cM[r][q2] = 0.f; dN[r][q2] = 0.f; cN[r][q2] = 0.f;
            nom[r][q2] = 0.f; den[r][q2] = 0.f;
        }

#pragma unroll
    for (int rr = 0; rr < 7; rr++) {
        const int iy = rb + rr;
        if ((unsigned)iy < NH) {
            const int roff = iy * NW + cb;
            float dv[8], cdv[8], sv[8], csv[8];
#pragma unroll
            for (int k = 0; k < 4; k++) {
                float2 vD, vCD, vS, vCS;
                if (slotok[k]) {
                    vD  = *(const float2*)(dp  + roff + 2 * k);
                    vCD = *(const float2*)(cdp + roff + 2 * k);
                    vS  = *(const float2*)(sp  + roff + 2 * k);
                    vCS = *(const float2*)(csp + roff + 2 * k);
                } else {
                    vD = make_float2(0.f, 0.f); vCD = vD; vS = vD; vCS = vD;
                }
                dv[2*k] = vD.x;  dv[2*k+1] = vD.y;
                cdv[2*k] = vCD.x; cdv[2*k+1] = vCD.y;
                sv[2*k] = vS.x;  sv[2*k+1] = vS.y;
                csv[2*k] = vCS.x; csv[2*k+1] = vCS.y;
            }
            float pm[7], pv[7];
#pragma unroll
            for (int ci = 0; ci < 7; ci++) {
                pm[ci] = dv[ci] * cdv[ci];            // IEEE f32, matches np
                pv[ci] = cdv[ci] / (dv[ci] + EPSF);   // IEEE f32 div, matches np
            }
#pragma unroll
            for (int r = 0; r < 2; r++) {
                const int dy = rr - 2 * r;            // compile-time under unroll
                if (dy >= 0 && dy <= 4) {
#pragma unroll
                    for (int dx = 0; dx < 5; dx++) {
                        const float w = sw_s[c * 25 + dy * 5 + dx];
#pragma unroll
                        for (int q2 = 0; q2 < 2; q2++) {
                            const int ci = 2 * q2 + dx;
                            if (ciok[ci]) {
                                if (pm[ci] > bm[r][q2]) { bm[r][q2] = pm[ci]; dM[r][q2] = dv[ci]; cM[r][q2] = cdv[ci]; }
                                if (pv[ci] > bn[r][q2]) { bn[r][q2] = pv[ci]; dN[r][q2] = dv[ci]; cN[r][q2] = cdv[ci]; }
                                nom[r][q2] += w * (csv[ci] * sv[ci]);
                                den[r][q2] += w * csv[ci];
                            }
                        }
                    }
                }
            }
        }
    }

#pragma unroll
    for (int r = 0; r < 2; r++)
#pragma unroll
        for (int q2 = 0; q2 < 2; q2++) {
            const float mdm  = fabsf(dN[r][q2] / (dM[r][q2] + EPSF));
            const float sfd  = (1.f - wsfd) * mdm + wsfd * mdm * mdm;
            const float cfd  = cM[r][q2] * cN[r][q2];
            const float ssp  = nom[r][q2] / (den[r][q2] + EPSF);
            const float cssp = den[r][q2] / (sumsw + EPSF);
            const int p = (tr * 2 + r) * TW + (q * 2 + q2);
            A_s[c][p] = cssp * ssp;
            B_s[c][p] = cssp;
            S_s[c][p] = sfd;
            C_s[c][p] = cfd;
        }
    __syncthreads();

    // ---------------- phase 2: channel mix + final combine ----------------
    const int p  = t & 31;
    const int o0 = t >> 5;              // 0..7
    const int py = p >> 3;
    const int pxx = p & 7;
    const int opx = (tile_y + py) * NWO + tile_x + pxx;

    float nom2[4], den2[4];
#pragma unroll
    for (int k = 0; k < 4; k++) { nom2[k] = 0.f; den2[k] = 0.f; }

#pragma unroll
    for (int i = 0; i < NC; i++) {
        const float a  = A_s[i][p];
        const float b2 = B_s[i][p];
#pragma unroll
        for (int k = 0; k < 4; k++) {
            const float w = cw_s[(o0 + 8 * k) * NC + i];
            nom2[k] += w * a;
            den2[k] += w * b2;
        }
    }

#pragma unroll
    for (int k = 0; k < 4; k++) {
        const int o = o0 + 8 * k;
        const float smix  = nom2[k] / (den2[k] + EPSF);
        const float csmix = den2[k] / (sumcw + EPSF);
        const float wp    = wp_s[o];
        const float sfd   = S_s[o][p];
        const float cfd   = C_s[o][p];

        float sout = (wp * csmix * smix + cfd * sfd) / (wp * csmix + cfd + EPSF);
        const float csout = (wp * csmix + cfd) / (wp + 1.f);

        sout += bias_s[o];
        sout = 1.f / (1.f + expf(-(sout * 2.f - 1.f))) * 0.5f + 0.5f;

        const int oidx = ((b * NC) + o) * NPX + opx;
        out[oidx]          = sout;
        out[NPLANE + oidx] = csout * 0.25f;
    }
}

extern "C" void kernel_launch(void* const* d_in, const int* in_sizes, int n_in,
                              void* d_out, int out_size, void* d_ws, size_t ws_size,
                              hipStream_t stream) {
    const float* d     = (const float*)d_in[0];
    const float* cd    = (const float*)d_in[1];
    const float* s     = (const float*)d_in[2];
    const float* cs    = (const float*)d_in[3];
    const float* wsfd  = (const float*)d_in[4];
    const float* wprop = (const float*)d_in[5];
    const float* spw   = (const float*)d_in[6];
    const float* chw   = (const float*)d_in[7];
    const float* bias  = (const float*)d_in[8];
    float* out = (float*)d_out;

    fused_kernel<<<dim3(NWO / TW, NHO / TH, NB), 256, 0, stream>>>(
        d, cd, s, cs, wsfd, wprop, spw, chw, bias, out);
}

// Round 5
// 70.758 us; speedup vs baseline: 1.5122x; 1.2541x over previous
//
#include <hip/hip_runtime.h>

// Problem constants (match reference)
#define KK    5
#define PADV  2
#define NB    4
#define NC    32
#define NH    192
#define NW    192
#define NHO   96
#define NWO   96
#define NPX   (NHO * NWO)        // 9216
#define NPLANE (NB * NC * NPX)   // 1,179,648
#define EPSF  1e-20f

__device__ __forceinline__ float softplusf(float x) {
    return fmaxf(x, 0.f) + log1pf(expf(-fabsf(x)));
}

// =====================================================================
// k1: per-(b, c, 4-row strip). Full-width 96x4 output tile.
//   Phase A: stage derived values for the 11x196 input patch into LDS
//            (parity-split columns -> phase B reads are stride-1).
//   Phase B: 1 output px per thread; 25-tap window from LDS.
//   Writes A,B,S,C f32 planes into ws.
// =====================================================================
#define TROWS 11
#define TCOLS 196
#define PLD   100   // parity array leading dim (>=98)

__global__ __launch_bounds__(384, 6) void k1(
    const float* __restrict__ dg,
    const float* __restrict__ cdg,
    const float* __restrict__ sg,
    const float* __restrict__ csg,
    const float* __restrict__ wsfdg,
    const float* __restrict__ spwg,
    float* __restrict__ ws)
{
    __shared__ float pm_e[TROWS][PLD], pm_o[TROWS][PLD];
    __shared__ float pv_e[TROWS][PLD], pv_o[TROWS][PLD];
    __shared__ float cs_e[TROWS][PLD], cs_o[TROWS][PLD];
    __shared__ float css_e[TROWS][PLD], css_o[TROWS][PLD];
    __shared__ float sw_row[25];
    __shared__ float red[6];
    __shared__ float scal[2];   // sumsw, wsfd

    const int t  = threadIdx.x;
    const int bx = blockIdx.x;   // y-strip 0..23
    const int c  = blockIdx.y;
    const int b  = blockIdx.z;

    // ---- phase 0: spatial weights (softplus row + global sum) ----
    float part = 0.f;
    for (int i = t; i < NC * 25; i += 384) {
        float v = softplusf(spwg[i]);
        part += v;
        int cr = i - c * 25;
        if (cr >= 0 && cr < 25) sw_row[cr] = v;
    }
#pragma unroll
    for (int m = 32; m >= 1; m >>= 1) part += __shfl_xor(part, m, 64);
    if ((t & 63) == 0) red[t >> 6] = part;
    __syncthreads();
    if (t == 0) {
        scal[0] = red[0] + red[1] + red[2] + red[3] + red[4] + red[5];
        scal[1] = 1.f / (1.f + expf(-wsfdg[0]));
    }
    __syncthreads();

    // ---- phase A: stage derived patch values ----
    const int gy0 = 8 * bx - 2;                    // top input row of patch
    const size_t base = ((size_t)(b * NC) + c) * (NH * NW);
#pragma unroll
    for (int it0 = 0; it0 < TROWS * TCOLS; it0 += 384) {
        const int it = it0 + t;
        if (it < TROWS * TCOLS) {
            const int r  = it / TCOLS;
            const int cc = it - r * TCOLS - 2;     // input col -2..193
            const int gy = gy0 + r;
            const bool ok = ((unsigned)gy < NH) && ((unsigned)cc < NW);
            float dv = 0.f, cdv = 0.f, sv = 0.f, csv = 0.f;
            if (ok) {
                const size_t idx = base + (size_t)gy * NW + cc;
                dv  = dg[idx];  cdv = cdg[idx];
                sv  = sg[idx];  csv = csg[idx];
            }
            const float pm   = ok ? dv * cdv : -INFINITY;       // IEEE f32
            const float pv   = ok ? cdv / (dv + EPSF) : -INFINITY;
            const float cssv = csv * sv;
            const int cp = cc + 2;                 // 0..195
            const int j  = cp >> 1;
            if (cp & 1) { pm_o[r][j] = pm; pv_o[r][j] = pv; cs_o[r][j] = csv; css_o[r][j] = cssv; }
            else        { pm_e[r][j] = pm; pv_e[r][j] = pv; cs_e[r][j] = csv; css_e[r][j] = cssv; }
        }
    }
    __syncthreads();

    // ---- phase B: one output px per thread ----
    const int p   = t;               // 0..383
    const int oyl = p / 96;          // 0..3
    const int ox  = p - oyl * 96;    // 0..95
    const int r0  = oyl * 2;

    float bm = -INFINITY, bv = -INFINITY;
    int   jm = 0, jv = 0;
    float nom = 0.f, den = 0.f;

#pragma unroll
    for (int dy = 0; dy < 5; dy++) {
        const int r = r0 + dy;
        const float w0 = sw_row[dy * 5 + 0];
        const float w1 = sw_row[dy * 5 + 1];
        const float w2 = sw_row[dy * 5 + 2];
        const float w3 = sw_row[dy * 5 + 3];
        const float w4 = sw_row[dy * 5 + 4];

        const float pme0 = pm_e[r][ox],     pve0 = pv_e[r][ox];
        const float pmo0 = pm_o[r][ox],     pvo0 = pv_o[r][ox];
        const float pme1 = pm_e[r][ox + 1], pve1 = pv_e[r][ox + 1];
        const float pmo1 = pm_o[r][ox + 1], pvo1 = pv_o[r][ox + 1];
        const float pme2 = pm_e[r][ox + 2], pve2 = pv_e[r][ox + 2];

        const float ce0 = cs_e[r][ox],      xe0 = css_e[r][ox];
        const float co0 = cs_o[r][ox],      xo0 = css_o[r][ox];
        const float ce1 = cs_e[r][ox + 1],  xe1 = css_e[r][ox + 1];
        const float co1 = cs_o[r][ox + 1],  xo1 = css_o[r][ox + 1];
        const float ce2 = cs_e[r][ox + 2],  xe2 = css_e[r][ox + 2];

        // taps in exact j order: dx = 0(e),1(o),2(e),3(o),4(e); strict > = first-max
        if (pme0 > bm) { bm = pme0; jm = r * 8 + 0; }
        if (pve0 > bv) { bv = pve0; jv = r * 8 + 0; }
        if (pmo0 > bm) { bm = pmo0; jm = r * 8 + 1; }
        if (pvo0 > bv) { bv = pvo0; jv = r * 8 + 1; }
        if (pme1 > bm) { bm = pme1; jm = r * 8 + 2; }
        if (pve1 > bv) { bv = pve1; jv = r * 8 + 2; }
        if (pmo1 > bm) { bm = pmo1; jm = r * 8 + 3; }
        if (pvo1 > bv) { bv = pvo1; jv = r * 8 + 3; }
        if (pme2 > bm) { bm = pme2; jm = r * 8 + 4; }
        if (pve2 > bv) { bv = pve2; jv = r * 8 + 4; }

        nom += w0 * xe0; den += w0 * ce0;
        nom += w1 * xo0; den += w1 * co0;
        nom += w2 * xe1; den += w2 * ce1;
        nom += w3 * xo1; den += w3 * co1;
        nom += w4 * xe2; den += w4 * ce2;
    }

    // decode winners, re-read d/cd at winning taps (L1/L2-hot)
    const int rm = jm >> 3, dxm = jm & 7;
    const int rv = jv >> 3, dxv = jv & 7;
    const size_t im = base + (size_t)(gy0 + rm) * NW + (2 * ox - 2 + dxm);
    const size_t iv = base + (size_t)(gy0 + rv) * NW + (2 * ox - 2 + dxv);
    const float dmax = dg[im], cdmax = cdg[im];
    const float dmin = dg[iv], cdmin = cdg[iv];

    const float sumsw = scal[0];
    const float wsfd  = scal[1];
    const float mdm  = fabsf(dmin / (dmax + EPSF));
    const float sfd  = (1.f - wsfd) * mdm + wsfd * mdm * mdm;
    const float cfd  = cdmax * cdmin;
    const float ssp  = nom / (den + EPSF);
    const float cssp = den / (sumsw + EPSF);

    const int opx = (4 * bx + oyl) * NWO + ox;
    const size_t oidx = ((size_t)(b * NC) + c) * NPX + opx;
    ws[oidx]                       = cssp * ssp;  // A
    ws[(size_t)NPLANE + oidx]      = cssp;        // B
    ws[2 * (size_t)NPLANE + oidx]  = sfd;         // S
    ws[3 * (size_t)NPLANE + oidx]  = cfd;         // C
}

// =====================================================================
// k2: channel mix + final combine (reads ws planes, writes outputs)
// =====================================================================
__global__ __launch_bounds__(256, 4) void k2(
    const float* __restrict__ ws,
    const float* __restrict__ wpropg,
    const float* __restrict__ chwg,
    const float* __restrict__ biasg,
    float* __restrict__ out)
{
    __shared__ float cw_s[NC * NC];
    __shared__ float wp_s[NC];
    __shared__ float bias_s[NC];
    __shared__ float red[4];
    __shared__ float scal[1];

    const int t  = threadIdx.x;
    const int b  = blockIdx.y;
    const int px = blockIdx.x * 256 + t;

    float part = 0.f;
    for (int i = t; i < NC * NC; i += 256) {
        float v = softplusf(chwg[i]); cw_s[i] = v; part += v;
    }
    if (t < NC) { wp_s[t] = softplusf(wpropg[t]); bias_s[t] = biasg[t]; }
#pragma unroll
    for (int m = 32; m >= 1; m >>= 1) part += __shfl_xor(part, m, 64);
    if ((t & 63) == 0) red[t >> 6] = part;
    __syncthreads();
    if (t == 0) scal[0] = red[0] + red[1] + red[2] + red[3];
    __syncthreads();
    const float sumcw = scal[0];

    // load A,B rows for all 32 input channels (coalesced, static index)
    float Av[NC], Bv[NC];
    const size_t bb = (size_t)b * NC * NPX;
#pragma unroll
    for (int i = 0; i < NC; i++) {
        Av[i] = ws[bb + (size_t)i * NPX + px];
        Bv[i] = ws[(size_t)NPLANE + bb + (size_t)i * NPX + px];
    }

#pragma unroll
    for (int o = 0; o < NC; o++) {
        float nom = 0.f, den = 0.f;
#pragma unroll
        for (int i = 0; i < NC; i++) {
            const float w = cw_s[o * NC + i];
            nom += w * Av[i];
            den += w * Bv[i];
        }
        const size_t oidx = bb + (size_t)o * NPX + px;
        const float sfd = ws[2 * (size_t)NPLANE + oidx];
        const float cfd = ws[3 * (size_t)NPLANE + oidx];

        const float smix  = nom / (den + EPSF);
        const float csmix = den / (sumcw + EPSF);
        const float wp    = wp_s[o];

        float sout = (wp * csmix * smix + cfd * sfd) / (wp * csmix + cfd + EPSF);
        const float csout = (wp * csmix + cfd) / (wp + 1.f);

        sout += bias_s[o];
        sout = 1.f / (1.f + expf(-(sout * 2.f - 1.f))) * 0.5f + 0.5f;

        out[oidx]                      = sout;
        out[(size_t)NPLANE + oidx]     = csout * 0.25f;
    }
}

// =====================================================================
// Fallback: round-4 fused kernel (used if ws_size is too small)
// =====================================================================
#define TW    8
#define TH    4
#define TPP   33

__global__ __launch_bounds__(256, 4) void fused_kernel(
    const float* __restrict__ dg,
    const float* __restrict__ cdg,
    const float* __restrict__ sg,
    const float* __restrict__ csg,
    const float* __restrict__ wsfdg,
    const float* __restrict__ wpropg,
    const float* __restrict__ spwg,
    const float* __restrict__ chwg,
    const float* __restrict__ biasg,
    float* __restrict__ out)
{
    __shared__ float sw_s[NC * 25];
    __shared__ float cw_s[NC * NC];
    __shared__ float wp_s[NC];
    __shared__ float bias_s[NC];
    __shared__ float A_s[NC][TPP];
    __shared__ float B_s[NC][TPP];
    __shared__ float S_s[NC][TPP];
    __shared__ float C_s[NC][TPP];
    __shared__ float red[8];
    __shared__ float scal[3];

    const int t = threadIdx.x;
    const int b = blockIdx.z;
    const int tile_x = blockIdx.x * TW;
    const int tile_y = blockIdx.y * TH;

    float p_sw = 0.f, p_cw = 0.f;
    for (int i = t; i < NC * 25; i += 256) { float v = softplusf(spwg[i]); sw_s[i] = v; p_sw += v; }
    for (int i = t; i < NC * NC; i += 256) { float v = softplusf(chwg[i]); cw_s[i] = v; p_cw += v; }
    if (t < NC) { wp_s[t] = softplusf(wpropg[t]); bias_s[t] = biasg[t]; }
#pragma unroll
    for (int m = 32; m >= 1; m >>= 1) {
        p_sw += __shfl_xor(p_sw, m, 64);
        p_cw += __shfl_xor(p_cw, m, 64);
    }
    if ((t & 63) == 0) { red[(t >> 6) * 2] = p_sw; red[(t >> 6) * 2 + 1] = p_cw; }
    __syncthreads();
    if (t == 0) {
        scal[0] = red[0] + red[2] + red[4] + red[6];
        scal[1] = red[1] + red[3] + red[5] + red[7];
        scal[2] = 1.f / (1.f + expf(-wsfdg[0]));
    }
    __syncthreads();

    const float sumsw = scal[0];
    const float sumcw = scal[1];
    const float wsfd  = scal[2];

    const int c  = t >> 3;
    const int tr = (t >> 2) & 1;
    const int q  = t & 3;
    const int oy0 = tile_y + tr * 2;
    const int ox0 = tile_x + q * 2;
    const int cb = ox0 * 2 - 2;
    const int rb = oy0 * 2 - 2;
    const size_t base = ((size_t)(b * NC) + c) * NH * NW;
    const float* __restrict__ dp  = dg  + base;
    const float* __restrict__ cdp = cdg + base;
    const float* __restrict__ sp  = sg  + base;
    const float* __restrict__ csp = csg + base;

    bool slotok[4];
#pragma unroll
    for (int k = 0; k < 4; k++) slotok[k] = (cb + 2 * k >= 0) && (cb + 2 * k + 1 < NW);
    bool ciok[7];
#pragma unroll
    for (int ci = 0; ci < 7; ci++) ciok[ci] = ((unsigned)(cb + ci) < NW);

    float bm[2][2], dM[2][2], cM[2][2];
    float bn[2][2], dN[2][2], cN[2][2];
    float nom[2][2], den[2][2];
#pragma unroll
    for (int r = 0; r < 2; r++)
#pragma unroll
        for (int q2 = 0; q2 < 2; q2++) {
            bm[r][q2] = -INFINITY; bn[r][q2] = -INFINITY;
            dM[r][q2] = 0.f; cM[r][q2] = 0.f; dN[r][q2] = 0.f; cN[r][q2] = 0.f;
            nom[r][q2] = 0.f; den[r][q2] = 0.f;
        }

#pragma unroll
    for (int rr = 0; rr < 7; rr++) {
        const int iy = rb + rr;
        if ((unsigned)iy < NH) {
            const int roff = iy * NW + cb;
            float dv[8], cdv[8], sv[8], csv[8];
#pragma unroll
            for (int k = 0; k < 4; k++) {
                float2 vD, vCD, vS, vCS;
                if (slotok[k]) {
                    vD  = *(const float2*)(dp  + roff + 2 * k);
                    vCD = *(const float2*)(cdp + roff + 2 * k);
                    vS  = *(const float2*)(sp  + roff + 2 * k);
                    vCS = *(const float2*)(csp + roff + 2 * k);
                } else {
                    vD = make_float2(0.f, 0.f); vCD = vD; vS = vD; vCS = vD;
                }
                dv[2*k] = vD.x;  dv[2*k+1] = vD.y;
                cdv[2*k] = vCD.x; cdv[2*k+1] = vCD.y;
                sv[2*k] = vS.x;  sv[2*k+1] = vS.y;
                csv[2*k] = vCS.x; csv[2*k+1] = vCS.y;
            }
            float pm[7], pv[7];
#pragma unroll
            for (int ci = 0; ci < 7; ci++) {
                pm[ci] = dv[ci] * cdv[ci];
                pv[ci] = cdv[ci] / (dv[ci] + EPSF);
            }
#pragma unroll
            for (int r = 0; r < 2; r++) {
                const int dy = rr - 2 * r;
                if (dy >= 0 && dy <= 4) {
#pragma unroll
                    for (int dx = 0; dx < 5; dx++) {
                        const float w = sw_s[c * 25 + dy * 5 + dx];
#pragma unroll
                        for (int q2 = 0; q2 < 2; q2++) {
                            const int ci = 2 * q2 + dx;
                            if (ciok[ci]) {
                                if (pm[ci] > bm[r][q2]) { bm[r][q2] = pm[ci]; dM[r][q2] = dv[ci]; cM[r][q2] = cdv[ci]; }
                                if (pv[ci] > bn[r][q2]) { bn[r][q2] = pv[ci]; dN[r][q2] = dv[ci]; cN[r][q2] = cdv[ci]; }
                                nom[r][q2] += w * (csv[ci] * sv[ci]);
                                den[r][q2] += w * csv[ci];
                            }
                        }
                    }
                }
            }
        }
    }

#pragma unroll
    for (int r = 0; r < 2; r++)
#pragma unroll
        for (int q2 = 0; q2 < 2; q2++) {
            const float mdm  = fabsf(dN[r][q2] / (dM[r][q2] + EPSF));
            const float sfd  = (1.f - wsfd) * mdm + wsfd * mdm * mdm;
            const float cfd  = cM[r][q2] * cN[r][q2];
            const float ssp  = nom[r][q2] / (den[r][q2] + EPSF);
            const float cssp = den[r][q2] / (sumsw + EPSF);
            const int p = (tr * 2 + r) * TW + (q * 2 + q2);
            A_s[c][p] = cssp * ssp;
            B_s[c][p] = cssp;
            S_s[c][p] = sfd;
            C_s[c][p] = cfd;
        }
    __syncthreads();

    const int p  = t & 31;
    const int o0 = t >> 5;
    const int py = p >> 3;
    const int pxx = p & 7;
    const int opx = (tile_y + py) * NWO + tile_x + pxx;

    float nom2[4], den2[4];
#pragma unroll
    for (int k = 0; k < 4; k++) { nom2[k] = 0.f; den2[k] = 0.f; }

#pragma unroll
    for (int i = 0; i < NC; i++) {
        const float a  = A_s[i][p];
        const float b2 = B_s[i][p];
#pragma unroll
        for (int k = 0; k < 4; k++) {
            const float w = cw_s[(o0 + 8 * k) * NC + i];
            nom2[k] += w * a;
            den2[k] += w * b2;
        }
    }

#pragma unroll
    for (int k = 0; k < 4; k++) {
        const int o = o0 + 8 * k;
        const float smix  = nom2[k] / (den2[k] + EPSF);
        const float csmix = den2[k] / (sumcw + EPSF);
        const float wp    = wp_s[o];
        const float sfd   = S_s[o][p];
        const float cfd   = C_s[o][p];

        float sout = (wp * csmix * smix + cfd * sfd) / (wp * csmix + cfd + EPSF);
        const float csout = (wp * csmix + cfd) / (wp + 1.f);

        sout += bias_s[o];
        sout = 1.f / (1.f + expf(-(sout * 2.f - 1.f))) * 0.5f + 0.5f;

        const int oidx = ((b * NC) + o) * NPX + opx;
        out[oidx]          = sout;
        out[NPLANE + oidx] = csout * 0.25f;
    }
}

extern "C" void kernel_launch(void* const* d_in, const int* in_sizes, int n_in,
                              void* d_out, int out_size, void* d_ws, size_t ws_size,
                              hipStream_t stream) {
    const float* d     = (const float*)d_in[0];
    const float* cd    = (const float*)d_in[1];
    const float* s     = (const float*)d_in[2];
    const float* cs    = (const float*)d_in[3];
    const float* wsfd  = (const float*)d_in[4];
    const float* wprop = (const float*)d_in[5];
    const float* spw   = (const float*)d_in[6];
    const float* chw   = (const float*)d_in[7];
    const float* bias  = (const float*)d_in[8];
    float* out = (float*)d_out;

    const size_t need = (size_t)4 * NPLANE * sizeof(float);   // 18.9 MB
    if (ws_size >= need) {
        float* ws = (float*)d_ws;
        k1<<<dim3(NHO / 4, NC, NB), 384, 0, stream>>>(d, cd, s, cs, wsfd, spw, ws);
        k2<<<dim3(NPX / 256, NB), 256, 0, stream>>>(ws, wprop, chw, bias, out);
    } else {
        fused_kernel<<<dim3(NWO / TW, NHO / TH, NB), 256, 0, stream>>>(
            d, cd, s, cs, wsfd, wprop, spw, chw, bias, out);
    }
}

// Round 6
// 47.432 us; speedup vs baseline: 2.2558x; 1.4918x over previous
//
#include <hip/hip_runtime.h>

// Problem constants (match reference)
#define KK    5
#define PADV  2
#define NB    4
#define NC    32
#define NH    192
#define NW    192
#define NHO   96
#define NWO   96
#define NPX   (NHO * NWO)        // 9216
#define NPLANE (NB * NC * NPX)   // 1,179,648
#define EPSF  1e-20f

__device__ __forceinline__ float softplusf(float x) {
    return fmaxf(x, 0.f) + log1pf(expf(-fabsf(x)));
}

// =====================================================================
// k1: per-(b, c, 8-row strip). Full-width 96x8 output tile, 768 threads.
//   Phase A: stage derived values for the 19x196 input patch into LDS
//            (parity-split columns -> phase B reads are stride-1).
//   Phase B: 1 output px per thread; 25-tap window from LDS.
//   Writes A,B,S,C f32 planes into ws.
// =====================================================================
#define TROWS 19
#define TCOLS 196
#define PLD   100   // parity array leading dim (>=98)
#define K1T   768

__global__ __launch_bounds__(K1T, 6) void k1(
    const float* __restrict__ dg,
    const float* __restrict__ cdg,
    const float* __restrict__ sg,
    const float* __restrict__ csg,
    const float* __restrict__ wsfdg,
    const float* __restrict__ spwg,
    float* __restrict__ ws)
{
    __shared__ float pm_e[TROWS][PLD], pm_o[TROWS][PLD];
    __shared__ float pv_e[TROWS][PLD], pv_o[TROWS][PLD];
    __shared__ float cs_e[TROWS][PLD], cs_o[TROWS][PLD];
    __shared__ float css_e[TROWS][PLD], css_o[TROWS][PLD];
    __shared__ float sw_row[25];
    __shared__ float red[12];
    __shared__ float scal[2];   // sumsw, wsfd

    const int t  = threadIdx.x;
    const int bx = blockIdx.x;   // y-strip 0..11
    const int c  = blockIdx.y;
    const int b  = blockIdx.z;

    // ---- phase 0: spatial weights (softplus row + global sum) ----
    float part = 0.f;
    for (int i = t; i < NC * 25; i += K1T) {
        float v = softplusf(spwg[i]);
        part += v;
        int cr = i - c * 25;
        if (cr >= 0 && cr < 25) sw_row[cr] = v;
    }
#pragma unroll
    for (int m = 32; m >= 1; m >>= 1) part += __shfl_xor(part, m, 64);
    if ((t & 63) == 0) red[t >> 6] = part;
    __syncthreads();
    if (t == 0) {
        float acc = 0.f;
#pragma unroll
        for (int i = 0; i < 12; i++) acc += red[i];
        scal[0] = acc;
        scal[1] = 1.f / (1.f + expf(-wsfdg[0]));
    }
    __syncthreads();

    // ---- phase A: stage derived patch values ----
    const int gy0 = 16 * bx - 2;                   // top input row of patch
    const size_t base = ((size_t)(b * NC) + c) * (NH * NW);
#pragma unroll
    for (int it0 = 0; it0 < TROWS * TCOLS; it0 += K1T) {
        const int it = it0 + t;
        if (it < TROWS * TCOLS) {
            const int r  = it / TCOLS;
            const int cc = it - r * TCOLS - 2;     // input col -2..193
            const int gy = gy0 + r;
            const bool ok = ((unsigned)gy < NH) && ((unsigned)cc < NW);
            float dv = 0.f, cdv = 0.f, sv = 0.f, csv = 0.f;
            if (ok) {
                const size_t idx = base + (size_t)gy * NW + cc;
                dv  = dg[idx];  cdv = cdg[idx];
                sv  = sg[idx];  csv = csg[idx];
            }
            const float pm   = ok ? dv * cdv : -INFINITY;       // IEEE f32
            const float pv   = ok ? cdv / (dv + EPSF) : -INFINITY;
            const float cssv = csv * sv;
            const int cp = cc + 2;                 // 0..195
            const int j  = cp >> 1;
            if (cp & 1) { pm_o[r][j] = pm; pv_o[r][j] = pv; cs_o[r][j] = csv; css_o[r][j] = cssv; }
            else        { pm_e[r][j] = pm; pv_e[r][j] = pv; cs_e[r][j] = csv; css_e[r][j] = cssv; }
        }
    }
    __syncthreads();

    // ---- phase B: one output px per thread ----
    const int oyl = t / 96;          // 0..7
    const int ox  = t - oyl * 96;    // 0..95
    const int r0  = oyl * 2;

    float bm = -INFINITY, bv = -INFINITY;
    int   jm = 0, jv = 0;
    float nom = 0.f, den = 0.f;

#pragma unroll
    for (int dy = 0; dy < 5; dy++) {
        const int r = r0 + dy;
        const float w0 = sw_row[dy * 5 + 0];
        const float w1 = sw_row[dy * 5 + 1];
        const float w2 = sw_row[dy * 5 + 2];
        const float w3 = sw_row[dy * 5 + 3];
        const float w4 = sw_row[dy * 5 + 4];

        const float pme0 = pm_e[r][ox],     pve0 = pv_e[r][ox];
        const float pmo0 = pm_o[r][ox],     pvo0 = pv_o[r][ox];
        const float pme1 = pm_e[r][ox + 1], pve1 = pv_e[r][ox + 1];
        const float pmo1 = pm_o[r][ox + 1], pvo1 = pv_o[r][ox + 1];
        const float pme2 = pm_e[r][ox + 2], pve2 = pv_e[r][ox + 2];

        const float ce0 = cs_e[r][ox],      xe0 = css_e[r][ox];
        const float co0 = cs_o[r][ox],      xo0 = css_o[r][ox];
        const float ce1 = cs_e[r][ox + 1],  xe1 = css_e[r][ox + 1];
        const float co1 = cs_o[r][ox + 1],  xo1 = css_o[r][ox + 1];
        const float ce2 = cs_e[r][ox + 2],  xe2 = css_e[r][ox + 2];

        // taps in exact j order: dx = 0(e),1(o),2(e),3(o),4(e); strict > = first-max
        if (pme0 > bm) { bm = pme0; jm = r * 8 + 0; }
        if (pve0 > bv) { bv = pve0; jv = r * 8 + 0; }
        if (pmo0 > bm) { bm = pmo0; jm = r * 8 + 1; }
        if (pvo0 > bv) { bv = pvo0; jv = r * 8 + 1; }
        if (pme1 > bm) { bm = pme1; jm = r * 8 + 2; }
        if (pve1 > bv) { bv = pve1; jv = r * 8 + 2; }
        if (pmo1 > bm) { bm = pmo1; jm = r * 8 + 3; }
        if (pvo1 > bv) { bv = pvo1; jv = r * 8 + 3; }
        if (pme2 > bm) { bm = pme2; jm = r * 8 + 4; }
        if (pve2 > bv) { bv = pve2; jv = r * 8 + 4; }

        nom += w0 * xe0; den += w0 * ce0;
        nom += w1 * xo0; den += w1 * co0;
        nom += w2 * xe1; den += w2 * ce1;
        nom += w3 * xo1; den += w3 * co1;
        nom += w4 * xe2; den += w4 * ce2;
    }

    // decode winners, re-read d/cd at winning taps (L1/L2-hot)
    const int rm = jm >> 3, dxm = jm & 7;
    const int rv = jv >> 3, dxv = jv & 7;
    const size_t im = base + (size_t)(gy0 + rm) * NW + (2 * ox - 2 + dxm);
    const size_t iv = base + (size_t)(gy0 + rv) * NW + (2 * ox - 2 + dxv);
    const float dmax = dg[im], cdmax = cdg[im];
    const float dmin = dg[iv], cdmin = cdg[iv];

    const float sumsw = scal[0];
    const float wsfd  = scal[1];
    const float mdm  = fabsf(dmin / (dmax + EPSF));
    const float sfd  = (1.f - wsfd) * mdm + wsfd * mdm * mdm;
    const float cfd  = cdmax * cdmin;
    const float ssp  = nom / (den + EPSF);
    const float cssp = den / (sumsw + EPSF);

    const int opx = (8 * bx + oyl) * NWO + ox;
    const size_t oidx = ((size_t)(b * NC) + c) * NPX + opx;
    ws[oidx]                       = cssp * ssp;  // A
    ws[(size_t)NPLANE + oidx]      = cssp;        // B
    ws[2 * (size_t)NPLANE + oidx]  = sfd;         // S
    ws[3 * (size_t)NPLANE + oidx]  = cfd;         // C
}

// =====================================================================
// k2: channel mix + final combine. 32-px tiles, 8 o-slots x 4 o's each.
// =====================================================================
#define K2PX 32

__global__ __launch_bounds__(256, 8) void k2(
    const float* __restrict__ ws,
    const float* __restrict__ wpropg,
    const float* __restrict__ chwg,
    const float* __restrict__ biasg,
    float* __restrict__ out)
{
    __shared__ float cw_s[NC * NC];
    __shared__ float wp_s[NC];
    __shared__ float bias_s[NC];
    __shared__ float A_s[NC][K2PX + 1];
    __shared__ float B_s[NC][K2PX + 1];
    __shared__ float red[4];
    __shared__ float scal[1];

    const int t    = threadIdx.x;
    const int b    = blockIdx.y;
    const int px0  = blockIdx.x * K2PX;
    const int p    = t & (K2PX - 1);     // 0..31
    const int slot = t >> 5;             // 0..7

    float part = 0.f;
    for (int i = t; i < NC * NC; i += 256) {
        float v = softplusf(chwg[i]); cw_s[i] = v; part += v;
    }
    if (t < NC) { wp_s[t] = softplusf(wpropg[t]); bias_s[t] = biasg[t]; }
#pragma unroll
    for (int m = 32; m >= 1; m >>= 1) part += __shfl_xor(part, m, 64);
    if ((t & 63) == 0) red[t >> 6] = part;
    __syncthreads();
    if (t == 0) scal[0] = red[0] + red[1] + red[2] + red[3];

    // stage A,B planes for this px tile (32 i x 32 px)
    const size_t bb = (size_t)b * NC * NPX;
#pragma unroll
    for (int idx = 0; idx < NC * K2PX; idx += 256) {
        const int i  = (idx + t) >> 5;
        const int pp = (idx + t) & (K2PX - 1);
        A_s[i][pp] = ws[bb + (size_t)i * NPX + px0 + pp];
        B_s[i][pp] = ws[(size_t)NPLANE + bb + (size_t)i * NPX + px0 + pp];
    }
    __syncthreads();

    const float sumcw = scal[0];
    const int px = px0 + p;

    float nom2[4], den2[4];
#pragma unroll
    for (int k = 0; k < 4; k++) { nom2[k] = 0.f; den2[k] = 0.f; }

#pragma unroll
    for (int i = 0; i < NC; i++) {
        const float a  = A_s[i][p];
        const float b2 = B_s[i][p];
#pragma unroll
        for (int k = 0; k < 4; k++) {
            const float w = cw_s[(slot + 8 * k) * NC + i];
            nom2[k] += w * a;
            den2[k] += w * b2;
        }
    }

#pragma unroll
    for (int k = 0; k < 4; k++) {
        const int o = slot + 8 * k;
        const size_t oidx = bb + (size_t)o * NPX + px;
        const float sfd = ws[2 * (size_t)NPLANE + oidx];
        const float cfd = ws[3 * (size_t)NPLANE + oidx];

        const float smix  = nom2[k] / (den2[k] + EPSF);
        const float csmix = den2[k] / (sumcw + EPSF);
        const float wp    = wp_s[o];

        float sout = (wp * csmix * smix + cfd * sfd) / (wp * csmix + cfd + EPSF);
        const float csout = (wp * csmix + cfd) / (wp + 1.f);

        sout += bias_s[o];
        sout = 1.f / (1.f + expf(-(sout * 2.f - 1.f))) * 0.5f + 0.5f;

        out[oidx]                  = sout;
        out[(size_t)NPLANE + oidx] = csout * 0.25f;
    }
}

// =====================================================================
// Fallback: round-4 fused kernel (used if ws_size is too small)
// =====================================================================
#define TW    8
#define TH    4
#define TPP   33

__global__ __launch_bounds__(256, 4) void fused_kernel(
    const float* __restrict__ dg,
    const float* __restrict__ cdg,
    const float* __restrict__ sg,
    const float* __restrict__ csg,
    const float* __restrict__ wsfdg,
    const float* __restrict__ wpropg,
    const float* __restrict__ spwg,
    const float* __restrict__ chwg,
    const float* __restrict__ biasg,
    float* __restrict__ out)
{
    __shared__ float sw_s[NC * 25];
    __shared__ float cw_s[NC * NC];
    __shared__ float wp_s[NC];
    __shared__ float bias_s[NC];
    __shared__ float A_s[NC][TPP];
    __shared__ float B_s[NC][TPP];
    __shared__ float S_s[NC][TPP];
    __shared__ float C_s[NC][TPP];
    __shared__ float red[8];
    __shared__ float scal[3];

    const int t = threadIdx.x;
    const int b = blockIdx.z;
    const int tile_x = blockIdx.x * TW;
    const int tile_y = blockIdx.y * TH;

    float p_sw = 0.f, p_cw = 0.f;
    for (int i = t; i < NC * 25; i += 256) { float v = softplusf(spwg[i]); sw_s[i] = v; p_sw += v; }
    for (int i = t; i < NC * NC; i += 256) { float v = softplusf(chwg[i]); cw_s[i] = v; p_cw += v; }
    if (t < NC) { wp_s[t] = softplusf(wpropg[t]); bias_s[t] = biasg[t]; }
#pragma unroll
    for (int m = 32; m >= 1; m >>= 1) {
        p_sw += __shfl_xor(p_sw, m, 64);
        p_cw += __shfl_xor(p_cw, m, 64);
    }
    if ((t & 63) == 0) { red[(t >> 6) * 2] = p_sw; red[(t >> 6) * 2 + 1] = p_cw; }
    __syncthreads();
    if (t == 0) {
        scal[0] = red[0] + red[2] + red[4] + red[6];
        scal[1] = red[1] + red[3] + red[5] + red[7];
        scal[2] = 1.f / (1.f + expf(-wsfdg[0]));
    }
    __syncthreads();

    const float sumsw = scal[0];
    const float sumcw = scal[1];
    const float wsfd  = scal[2];

    const int c  = t >> 3;
    const int tr = (t >> 2) & 1;
    const int q  = t & 3;
    const int oy0 = tile_y + tr * 2;
    const int ox0 = tile_x + q * 2;
    const int cb = ox0 * 2 - 2;
    const int rb = oy0 * 2 - 2;
    const size_t base = ((size_t)(b * NC) + c) * NH * NW;
    const float* __restrict__ dp  = dg  + base;
    const float* __restrict__ cdp = cdg + base;
    const float* __restrict__ sp  = sg  + base;
    const float* __restrict__ csp = csg + base;

    bool slotok[4];
#pragma unroll
    for (int k = 0; k < 4; k++) slotok[k] = (cb + 2 * k >= 0) && (cb + 2 * k + 1 < NW);
    bool ciok[7];
#pragma unroll
    for (int ci = 0; ci < 7; ci++) ciok[ci] = ((unsigned)(cb + ci) < NW);

    float bm[2][2], dM[2][2], cM[2][2];
    float bn[2][2], dN[2][2], cN[2][2];
    float nom[2][2], den[2][2];
#pragma unroll
    for (int r = 0; r < 2; r++)
#pragma unroll
        for (int q2 = 0; q2 < 2; q2++) {
            bm[r][q2] = -INFINITY; bn[r][q2] = -INFINITY;
            dM[r][q2] = 0.f; cM[r][q2] = 0.f; dN[r][q2] = 0.f; cN[r][q2] = 0.f;
            nom[r][q2] = 0.f; den[r][q2] = 0.f;
        }

#pragma unroll
    for (int rr = 0; rr < 7; rr++) {
        const int iy = rb + rr;
        if ((unsigned)iy < NH) {
            const int roff = iy * NW + cb;
            float dv[8], cdv[8], sv[8], csv[8];
#pragma unroll
            for (int k = 0; k < 4; k++) {
                float2 vD, vCD, vS, vCS;
                if (slotok[k]) {
                    vD  = *(const float2*)(dp  + roff + 2 * k);
                    vCD = *(const float2*)(cdp + roff + 2 * k);
                    vS  = *(const float2*)(sp  + roff + 2 * k);
                    vCS = *(const float2*)(csp + roff + 2 * k);
                } else {
                    vD = make_float2(0.f, 0.f); vCD = vD; vS = vD; vCS = vD;
                }
                dv[2*k] = vD.x;  dv[2*k+1] = vD.y;
                cdv[2*k] = vCD.x; cdv[2*k+1] = vCD.y;
                sv[2*k] = vS.x;  sv[2*k+1] = vS.y;
                csv[2*k] = vCS.x; csv[2*k+1] = vCS.y;
            }
            float pm[7], pv[7];
#pragma unroll
            for (int ci = 0; ci < 7; ci++) {
                pm[ci] = dv[ci] * cdv[ci];
                pv[ci] = cdv[ci] / (dv[ci] + EPSF);
            }
#pragma unroll
            for (int r = 0; r < 2; r++) {
                const int dy = rr - 2 * r;
                if (dy >= 0 && dy <= 4) {
#pragma unroll
                    for (int dx = 0; dx < 5; dx++) {
                        const float w = sw_s[c * 25 + dy * 5 + dx];
#pragma unroll
                        for (int q2 = 0; q2 < 2; q2++) {
                            const int ci = 2 * q2 + dx;
                            if (ciok[ci]) {
                                if (pm[ci] > bm[r][q2]) { bm[r][q2] = pm[ci]; dM[r][q2] = dv[ci]; cM[r][q2] = cdv[ci]; }
                                if (pv[ci] > bn[r][q2]) { bn[r][q2] = pv[ci]; dN[r][q2] = dv[ci]; cN[r][q2] = cdv[ci]; }
                                nom[r][q2] += w * (csv[ci] * sv[ci]);
                                den[r][q2] += w * csv[ci];
                            }
                        }
                    }
                }
            }
        }
    }

#pragma unroll
    for (int r = 0; r < 2; r++)
#pragma unroll
        for (int q2 = 0; q2 < 2; q2++) {
            const float mdm  = fabsf(dN[r][q2] / (dM[r][q2] + EPSF));
            const float sfd  = (1.f - wsfd) * mdm + wsfd * mdm * mdm;
            const float cfd  = cM[r][q2] * cN[r][q2];
            const float ssp  = nom[r][q2] / (den[r][q2] + EPSF);
            const float cssp = den[r][q2] / (sumsw + EPSF);
            const int p = (tr * 2 + r) * TW + (q * 2 + q2);
            A_s[c][p] = cssp * ssp;
            B_s[c][p] = cssp;
            S_s[c][p] = sfd;
            C_s[c][p] = cfd;
        }
    __syncthreads();

    const int p  = t & 31;
    const int o0 = t >> 5;
    const int py = p >> 3;
    const int pxx = p & 7;
    const int opx = (tile_y + py) * NWO + tile_x + pxx;

    float nom2[4], den2[4];
#pragma unroll
    for (int k = 0; k < 4; k++) { nom2[k] = 0.f; den2[k] = 0.f; }

#pragma unroll
    for (int i = 0; i < NC; i++) {
        const float a  = A_s[i][p];
        const float b2 = B_s[i][p];
#pragma unroll
        for (int k = 0; k < 4; k++) {
            const float w = cw_s[(o0 + 8 * k) * NC + i];
            nom2[k] += w * a;
            den2[k] += w * b2;
        }
    }

#pragma unroll
    for (int k = 0; k < 4; k++) {
        const int o = o0 + 8 * k;
        const float smix  = nom2[k] / (den2[k] + EPSF);
        const float csmix = den2[k] / (sumcw + EPSF);
        const float wp    = wp_s[o];
        const float sfd   = S_s[o][p];
        const float cfd   = C_s[o][p];

        float sout = (wp * csmix * smix + cfd * sfd) / (wp * csmix + cfd + EPSF);
        const float csout = (wp * csmix + cfd) / (wp + 1.f);

        sout += bias_s[o];
        sout = 1.f / (1.f + expf(-(sout * 2.f - 1.f))) * 0.5f + 0.5f;

        const int oidx = ((b * NC) + o) * NPX + opx;
        out[oidx]          = sout;
        out[NPLANE + oidx] = csout * 0.25f;
    }
}

extern "C" void kernel_launch(void* const* d_in, const int* in_sizes, int n_in,
                              void* d_out, int out_size, void* d_ws, size_t ws_size,
                              hipStream_t stream) {
    const float* d     = (const float*)d_in[0];
    const float* cd    = (const float*)d_in[1];
    const float* s     = (const float*)d_in[2];
    const float* cs    = (const float*)d_in[3];
    const float* wsfd  = (const float*)d_in[4];
    const float* wprop = (const float*)d_in[5];
    const float* spw   = (const float*)d_in[6];
    const float* chw   = (const float*)d_in[7];
    const float* bias  = (const float*)d_in[8];
    float* out = (float*)d_out;

    const size_t need = (size_t)4 * NPLANE * sizeof(float);   // 18.9 MB
    if (ws_size >= need) {
        float* ws = (float*)d_ws;
        k1<<<dim3(NHO / 8, NC, NB), K1T, 0, stream>>>(d, cd, s, cs, wsfd, spw, ws);
        k2<<<dim3(NPX / K2PX, NB), 256, 0, stream>>>(ws, wprop, chw, bias, out);
    } else {
        fused_kernel<<<dim3(NWO / TW, NHO / TH, NB), 256, 0, stream>>>(
            d, cd, s, cs, wsfd, wprop, spw, chw, bias, out);
    }
}

// Round 7
// 46.400 us; speedup vs baseline: 2.3060x; 1.0222x over previous
//
#include <hip/hip_runtime.h>

// Problem constants (match reference)
#define KK    5
#define PADV  2
#define NB    4
#define NC    32
#define NH    192
#define NW    192
#define NHO   96
#define NWO   96
#define NPX   (NHO * NWO)        // 9216
#define NPLANE (NB * NC * NPX)   // 1,179,648
#define EPSF  1e-20f

__device__ __forceinline__ float softplusf(float x) {
    return fmaxf(x, 0.f) + log1pf(expf(-fabsf(x)));
}

// =====================================================================
// k1: per-(b, c, 8-row strip). Full-width 96x8 output tile, 768 threads.
//   Phase A: stage float2-packed derived values for the 19x196 patch:
//            pmv = (d*cd, cd/(d+eps)), csss = (cs, cs*s), parity-split.
//   Phase B: 1 output px per thread; 25-tap window, b64 LDS reads.
// =====================================================================
#define TROWS 19
#define NJ    98    // column pairs (parity index 0..97)
#define PLD2  100   // padded leading dim (float2 elements)
#define K1T   768

__global__ __launch_bounds__(K1T, 6) void k1(
    const float* __restrict__ dg,
    const float* __restrict__ cdg,
    const float* __restrict__ sg,
    const float* __restrict__ csg,
    const float* __restrict__ wsfdg,
    const float* __restrict__ spwg,
    float* __restrict__ ws)
{
    __shared__ float2 pmv_e[TROWS][PLD2];   // (pm, pv) even cols
    __shared__ float2 pmv_o[TROWS][PLD2];   // (pm, pv) odd cols
    __shared__ float2 csss_e[TROWS][PLD2];  // (cs, cs*s) even cols
    __shared__ float2 csss_o[TROWS][PLD2];  // (cs, cs*s) odd cols
    __shared__ float sw_row[25];
    __shared__ float red[12];
    __shared__ float scal[2];   // sumsw, wsfd

    const int t  = threadIdx.x;
    const int bx = blockIdx.x;   // y-strip 0..11
    const int c  = blockIdx.y;
    const int b  = blockIdx.z;

    // ---- phase 0: spatial weights (softplus row + global sum) ----
    float part = 0.f;
    for (int i = t; i < NC * 25; i += K1T) {
        float v = softplusf(spwg[i]);
        part += v;
        int cr = i - c * 25;
        if (cr >= 0 && cr < 25) sw_row[cr] = v;
    }
#pragma unroll
    for (int m = 32; m >= 1; m >>= 1) part += __shfl_xor(part, m, 64);
    if ((t & 63) == 0) red[t >> 6] = part;
    __syncthreads();
    if (t == 0) {
        float acc = 0.f;
#pragma unroll
        for (int i = 0; i < 12; i++) acc += red[i];
        scal[0] = acc;
        scal[1] = 1.f / (1.f + expf(-wsfdg[0]));
    }
    __syncthreads();

    // ---- phase A: stage packed derived patch values ----
    const int gy0 = 16 * bx - 2;                   // top input row of patch
    const size_t base = ((size_t)(b * NC) + c) * (NH * NW);
    const int ITEMS = TROWS * NJ;                  // 1862
#pragma unroll
    for (int it0 = 0; it0 < 3 * K1T; it0 += K1T) {
        const int it = it0 + t;
        if (it < ITEMS) {
            const int r  = it / NJ;
            const int j  = it - r * NJ;            // parity index 0..97
            const int gy = gy0 + r;
            const int cc = 2 * j - 2;              // even input col of the pair
            // pair is all-in-bounds (j=1..96, row ok) or all-out
            const bool ok = ((unsigned)gy < NH) && (j >= 1) && (j <= 96);
            float2 dv2 = make_float2(0.f, 0.f), cdv2 = dv2, sv2 = dv2, csv2 = dv2;
            if (ok) {
                const size_t idx = base + (size_t)gy * NW + cc;   // 8B-aligned
                dv2  = *(const float2*)(dg  + idx);
                cdv2 = *(const float2*)(cdg + idx);
                sv2  = *(const float2*)(sg  + idx);
                csv2 = *(const float2*)(csg + idx);
            }
            float2 pe, po, ce, co;
            if (ok) {
                pe = make_float2(dv2.x * cdv2.x, cdv2.x / (dv2.x + EPSF));  // IEEE f32
                po = make_float2(dv2.y * cdv2.y, cdv2.y / (dv2.y + EPSF));
            } else {
                pe = make_float2(-INFINITY, -INFINITY);
                po = pe;
            }
            ce = make_float2(csv2.x, csv2.x * sv2.x);
            co = make_float2(csv2.y, csv2.y * sv2.y);
            pmv_e[r][j]  = pe;
            pmv_o[r][j]  = po;
            csss_e[r][j] = ce;
            csss_o[r][j] = co;
        }
    }
    __syncthreads();

    // ---- phase B: one output px per thread ----
    const int oyl = t / 96;          // 0..7
    const int ox  = t - oyl * 96;    // 0..95
    const int r0  = oyl * 2;

    float bm = -INFINITY, bv = -INFINITY;
    int   jm = 0, jv = 0;
    float nom = 0.f, den = 0.f;

#pragma unroll
    for (int dy = 0; dy < 5; dy++) {
        const int r = r0 + dy;
        const float w0 = sw_row[dy * 5 + 0];
        const float w1 = sw_row[dy * 5 + 1];
        const float w2 = sw_row[dy * 5 + 2];
        const float w3 = sw_row[dy * 5 + 3];
        const float w4 = sw_row[dy * 5 + 4];

        const float2 e0 = pmv_e[r][ox];       // (pm, pv) dx=0
        const float2 o0 = pmv_o[r][ox];       // dx=1
        const float2 e1 = pmv_e[r][ox + 1];   // dx=2
        const float2 o1 = pmv_o[r][ox + 1];   // dx=3
        const float2 e2 = pmv_e[r][ox + 2];   // dx=4

        const float2 c0 = csss_e[r][ox];      // (cs, cs*s)
        const float2 d1 = csss_o[r][ox];
        const float2 c1 = csss_e[r][ox + 1];
        const float2 d3 = csss_o[r][ox + 1];
        const float2 c2 = csss_e[r][ox + 2];

        // taps in exact j order: dx = 0,1,2,3,4; strict > = first-max
        if (e0.x > bm) { bm = e0.x; jm = r * 8 + 0; }
        if (e0.y > bv) { bv = e0.y; jv = r * 8 + 0; }
        if (o0.x > bm) { bm = o0.x; jm = r * 8 + 1; }
        if (o0.y > bv) { bv = o0.y; jv = r * 8 + 1; }
        if (e1.x > bm) { bm = e1.x; jm = r * 8 + 2; }
        if (e1.y > bv) { bv = e1.y; jv = r * 8 + 2; }
        if (o1.x > bm) { bm = o1.x; jm = r * 8 + 3; }
        if (o1.y > bv) { bv = o1.y; jv = r * 8 + 3; }
        if (e2.x > bm) { bm = e2.x; jm = r * 8 + 4; }
        if (e2.y > bv) { bv = e2.y; jv = r * 8 + 4; }

        nom += w0 * c0.y; den += w0 * c0.x;
        nom += w1 * d1.y; den += w1 * d1.x;
        nom += w2 * c1.y; den += w2 * c1.x;
        nom += w3 * d3.y; den += w3 * d3.x;
        nom += w4 * c2.y; den += w4 * c2.x;
    }

    // decode winners, re-read d/cd at winning taps (L1/L2-hot)
    const int rm = jm >> 3, dxm = jm & 7;
    const int rv = jv >> 3, dxv = jv & 7;
    const size_t im = base + (size_t)(gy0 + rm) * NW + (2 * ox - 2 + dxm);
    const size_t iv = base + (size_t)(gy0 + rv) * NW + (2 * ox - 2 + dxv);
    const float dmax = dg[im], cdmax = cdg[im];
    const float dmin = dg[iv], cdmin = cdg[iv];

    const float sumsw = scal[0];
    const float wsfd  = scal[1];
    const float mdm  = fabsf(dmin / (dmax + EPSF));
    const float sfd  = (1.f - wsfd) * mdm + wsfd * mdm * mdm;
    const float cfd  = cdmax * cdmin;
    const float ssp  = nom / (den + EPSF);
    const float cssp = den / (sumsw + EPSF);

    const int opx = (8 * bx + oyl) * NWO + ox;
    const size_t oidx = ((size_t)(b * NC) + c) * NPX + opx;
    ws[oidx]                       = cssp * ssp;  // A
    ws[(size_t)NPLANE + oidx]      = cssp;        // B
    ws[2 * (size_t)NPLANE + oidx]  = sfd;         // S
    ws[3 * (size_t)NPLANE + oidx]  = cfd;         // C
}

// =====================================================================
// k2: channel mix + final combine. 32-px tiles, 8 o-slots x 4 o's each.
// =====================================================================
#define K2PX 32

__global__ __launch_bounds__(256, 8) void k2(
    const float* __restrict__ ws,
    const float* __restrict__ wpropg,
    const float* __restrict__ chwg,
    const float* __restrict__ biasg,
    float* __restrict__ out)
{
    __shared__ float cw_s[NC * NC];
    __shared__ float wp_s[NC];
    __shared__ float bias_s[NC];
    __shared__ float A_s[NC][K2PX + 1];
    __shared__ float B_s[NC][K2PX + 1];
    __shared__ float red[4];
    __shared__ float scal[1];

    const int t    = threadIdx.x;
    const int b    = blockIdx.y;
    const int px0  = blockIdx.x * K2PX;
    const int p    = t & (K2PX - 1);     // 0..31
    const int slot = t >> 5;             // 0..7

    float part = 0.f;
    for (int i = t; i < NC * NC; i += 256) {
        float v = softplusf(chwg[i]); cw_s[i] = v; part += v;
    }
    if (t < NC) { wp_s[t] = softplusf(wpropg[t]); bias_s[t] = biasg[t]; }
#pragma unroll
    for (int m = 32; m >= 1; m >>= 1) part += __shfl_xor(part, m, 64);
    if ((t & 63) == 0) red[t >> 6] = part;
    __syncthreads();
    if (t == 0) scal[0] = red[0] + red[1] + red[2] + red[3];

    // stage A,B planes for this px tile (32 i x 32 px)
    const size_t bb = (size_t)b * NC * NPX;
#pragma unroll
    for (int idx = 0; idx < NC * K2PX; idx += 256) {
        const int i  = (idx + t) >> 5;
        const int pp = (idx + t) & (K2PX - 1);
        A_s[i][pp] = ws[bb + (size_t)i * NPX + px0 + pp];
        B_s[i][pp] = ws[(size_t)NPLANE + bb + (size_t)i * NPX + px0 + pp];
    }
    __syncthreads();

    const float sumcw = scal[0];
    const int px = px0 + p;

    float nom2[4], den2[4];
#pragma unroll
    for (int k = 0; k < 4; k++) { nom2[k] = 0.f; den2[k] = 0.f; }

#pragma unroll
    for (int i = 0; i < NC; i++) {
        const float a  = A_s[i][p];
        const float b2 = B_s[i][p];
#pragma unroll
        for (int k = 0; k < 4; k++) {
            const float w = cw_s[(slot + 8 * k) * NC + i];
            nom2[k] += w * a;
            den2[k] += w * b2;
        }
    }

#pragma unroll
    for (int k = 0; k < 4; k++) {
        const int o = slot + 8 * k;
        const size_t oidx = bb + (size_t)o * NPX + px;
        const float sfd = ws[2 * (size_t)NPLANE + oidx];
        const float cfd = ws[3 * (size_t)NPLANE + oidx];

        const float smix  = nom2[k] / (den2[k] + EPSF);
        const float csmix = den2[k] / (sumcw + EPSF);
        const float wp    = wp_s[o];

        float sout = (wp * csmix * smix + cfd * sfd) / (wp * csmix + cfd + EPSF);
        const float csout = (wp * csmix + cfd) / (wp + 1.f);

        sout += bias_s[o];
        sout = 1.f / (1.f + expf(-(sout * 2.f - 1.f))) * 0.5f + 0.5f;

        out[oidx]                  = sout;
        out[(size_t)NPLANE + oidx] = csout * 0.25f;
    }
}

// =====================================================================
// Fallback: round-4 fused kernel (used if ws_size is too small)
// =====================================================================
#define TW    8
#define TH    4
#define TPP   33

__global__ __launch_bounds__(256, 4) void fused_kernel(
    const float* __restrict__ dg,
    const float* __restrict__ cdg,
    const float* __restrict__ sg,
    const float* __restrict__ csg,
    const float* __restrict__ wsfdg,
    const float* __restrict__ wpropg,
    const float* __restrict__ spwg,
    const float* __restrict__ chwg,
    const float* __restrict__ biasg,
    float* __restrict__ out)
{
    __shared__ float sw_s[NC * 25];
    __shared__ float cw_s[NC * NC];
    __shared__ float wp_s[NC];
    __shared__ float bias_s[NC];
    __shared__ float A_s[NC][TPP];
    __shared__ float B_s[NC][TPP];
    __shared__ float S_s[NC][TPP];
    __shared__ float C_s[NC][TPP];
    __shared__ float red[8];
    __shared__ float scal[3];

    const int t = threadIdx.x;
    const int b = blockIdx.z;
    const int tile_x = blockIdx.x * TW;
    const int tile_y = blockIdx.y * TH;

    float p_sw = 0.f, p_cw = 0.f;
    for (int i = t; i < NC * 25; i += 256) { float v = softplusf(spwg[i]); sw_s[i] = v; p_sw += v; }
    for (int i = t; i < NC * NC; i += 256) { float v = softplusf(chwg[i]); cw_s[i] = v; p_cw += v; }
    if (t < NC) { wp_s[t] = softplusf(wpropg[t]); bias_s[t] = biasg[t]; }
#pragma unroll
    for (int m = 32; m >= 1; m >>= 1) {
        p_sw += __shfl_xor(p_sw, m, 64);
        p_cw += __shfl_xor(p_cw, m, 64);
    }
    if ((t & 63) == 0) { red[(t >> 6) * 2] = p_sw; red[(t >> 6) * 2 + 1] = p_cw; }
    __syncthreads();
    if (t == 0) {
        scal[0] = red[0] + red[2] + red[4] + red[6];
        scal[1] = red[1] + red[3] + red[5] + red[7];
        scal[2] = 1.f / (1.f + expf(-wsfdg[0]));
    }
    __syncthreads();

    const float sumsw = scal[0];
    const float sumcw = scal[1];
    const float wsfd  = scal[2];

    const int c  = t >> 3;
    const int tr = (t >> 2) & 1;
    const int q  = t & 3;
    const int oy0 = tile_y + tr * 2;
    const int ox0 = tile_x + q * 2;
    const int cb = ox0 * 2 - 2;
    const int rb = oy0 * 2 - 2;
    const size_t base = ((size_t)(b * NC) + c) * NH * NW;
    const float* __restrict__ dp  = dg  + base;
    const float* __restrict__ cdp = cdg + base;
    const float* __restrict__ sp  = sg  + base;
    const float* __restrict__ csp = csg + base;

    bool slotok[4];
#pragma unroll
    for (int k = 0; k < 4; k++) slotok[k] = (cb + 2 * k >= 0) && (cb + 2 * k + 1 < NW);
    bool ciok[7];
#pragma unroll
    for (int ci = 0; ci < 7; ci++) ciok[ci] = ((unsigned)(cb + ci) < NW);

    float bm[2][2], dM[2][2], cM[2][2];
    float bn[2][2], dN[2][2], cN[2][2];
    float nom[2][2], den[2][2];
#pragma unroll
    for (int r = 0; r < 2; r++)
#pragma unroll
        for (int q2 = 0; q2 < 2; q2++) {
            bm[r][q2] = -INFINITY; bn[r][q2] = -INFINITY;
            dM[r][q2] = 0.f; cM[r][q2] = 0.f; dN[r][q2] = 0.f; cN[r][q2] = 0.f;
            nom[r][q2] = 0.f; den[r][q2] = 0.f;
        }

#pragma unroll
    for (int rr = 0; rr < 7; rr++) {
        const int iy = rb + rr;
        if ((unsigned)iy < NH) {
            const int roff = iy * NW + cb;
            float dv[8], cdv[8], sv[8], csv[8];
#pragma unroll
            for (int k = 0; k < 4; k++) {
                float2 vD, vCD, vS, vCS;
                if (slotok[k]) {
                    vD  = *(const float2*)(dp  + roff + 2 * k);
                    vCD = *(const float2*)(cdp + roff + 2 * k);
                    vS  = *(const float2*)(sp  + roff + 2 * k);
                    vCS = *(const float2*)(csp + roff + 2 * k);
                } else {
                    vD = make_float2(0.f, 0.f); vCD = vD; vS = vD; vCS = vD;
                }
                dv[2*k] = vD.x;  dv[2*k+1] = vD.y;
                cdv[2*k] = vCD.x; cdv[2*k+1] = vCD.y;
                sv[2*k] = vS.x;  sv[2*k+1] = vS.y;
                csv[2*k] = vCS.x; csv[2*k+1] = vCS.y;
            }
            float pm[7], pv[7];
#pragma unroll
            for (int ci = 0; ci < 7; ci++) {
                pm[ci] = dv[ci] * cdv[ci];
                pv[ci] = cdv[ci] / (dv[ci] + EPSF);
            }
#pragma unroll
            for (int r = 0; r < 2; r++) {
                const int dy = rr - 2 * r;
                if (dy >= 0 && dy <= 4) {
#pragma unroll
                    for (int dx = 0; dx < 5; dx++) {
                        const float w = sw_s[c * 25 + dy * 5 + dx];
#pragma unroll
                        for (int q2 = 0; q2 < 2; q2++) {
                            const int ci = 2 * q2 + dx;
                            if (ciok[ci]) {
                                if (pm[ci] > bm[r][q2]) { bm[r][q2] = pm[ci]; dM[r][q2] = dv[ci]; cM[r][q2] = cdv[ci]; }
                                if (pv[ci] > bn[r][q2]) { bn[r][q2] = pv[ci]; dN[r][q2] = dv[ci]; cN[r][q2] = cdv[ci]; }
                                nom[r][q2] += w * (csv[ci] * sv[ci]);
                                den[r][q2] += w * csv[ci];
                            }
                        }
                    }
                }
            }
        }
    }

#pragma unroll
    for (int r = 0; r < 2; r++)
#pragma unroll
        for (int q2 = 0; q2 < 2; q2++) {
            const float mdm  = fabsf(dN[r][q2] / (dM[r][q2] + EPSF));
            const float sfd  = (1.f - wsfd) * mdm + wsfd * mdm * mdm;
            const float cfd  = cM[r][q2] * cN[r][q2];
            const float ssp  = nom[r][q2] / (den[r][q2] + EPSF);
            const float cssp = den[r][q2] / (sumsw + EPSF);
            const int p = (tr * 2 + r) * TW + (q * 2 + q2);
            A_s[c][p] = cssp * ssp;
            B_s[c][p] = cssp;
            S_s[c][p] = sfd;
            C_s[c][p] = cfd;
        }
    __syncthreads();

    const int p  = t & 31;
    const int o0 = t >> 5;
    const int py = p >> 3;
    const int pxx = p & 7;
    const int opx = (tile_y + py) * NWO + tile_x + pxx;

    float nom2[4], den2[4];
#pragma unroll
    for (int k = 0; k < 4; k++) { nom2[k] = 0.f; den2[k] = 0.f; }

#pragma unroll
    for (int i = 0; i < NC; i++) {
        const float a  = A_s[i][p];
        const float b2 = B_s[i][p];
#pragma unroll
        for (int k = 0; k < 4; k++) {
            const float w = cw_s[(o0 + 8 * k) * NC + i];
            nom2[k] += w * a;
            den2[k] += w * b2;
        }
    }

#pragma unroll
    for (int k = 0; k < 4; k++) {
        const int o = o0 + 8 * k;
        const float smix  = nom2[k] / (den2[k] + EPSF);
        const float csmix = den2[k] / (sumcw + EPSF);
        const float wp    = wp_s[o];
        const float sfd   = S_s[o][p];
        const float cfd   = C_s[o][p];

        float sout = (wp * csmix * smix + cfd * sfd) / (wp * csmix + cfd + EPSF);
        const float csout = (wp * csmix + cfd) / (wp + 1.f);

        sout += bias_s[o];
        sout = 1.f / (1.f + expf(-(sout * 2.f - 1.f))) * 0.5f + 0.5f;

        const int oidx = ((b * NC) + o) * NPX + opx;
        out[oidx]          = sout;
        out[NPLANE + oidx] = csout * 0.25f;
    }
}

extern "C" void kernel_launch(void* const* d_in, const int* in_sizes, int n_in,
                              void* d_out, int out_size, void* d_ws, size_t ws_size,
                              hipStream_t stream) {
    const float* d     = (const float*)d_in[0];
    const float* cd    = (const float*)d_in[1];
    const float* s     = (const float*)d_in[2];
    const float* cs    = (const float*)d_in[3];
    const float* wsfd  = (const float*)d_in[4];
    const float* wprop = (const float*)d_in[5];
    const float* spw   = (const float*)d_in[6];
    const float* chw   = (const float*)d_in[7];
    const float* bias  = (const float*)d_in[8];
    float* out = (float*)d_out;

    const size_t need = (size_t)4 * NPLANE * sizeof(float);   // 18.9 MB
    if (ws_size >= need) {
        float* ws = (float*)d_ws;
        k1<<<dim3(NHO / 8, NC, NB), K1T, 0, stream>>>(d, cd, s, cs, wsfd, spw, ws);
        k2<<<dim3(NPX / K2PX, NB), 256, 0, stream>>>(ws, wprop, chw, bias, out);
    } else {
        fused_kernel<<<dim3(NWO / TW, NHO / TH, NB), 256, 0, stream>>>(
            d, cd, s, cs, wsfd, wprop, spw, chw, bias, out);
    }
}